// Round 1
// baseline (859.957 us; speedup 1.0000x reference)
//
#include <hip/hip_runtime.h>

#define NF 26
#define NB 16384
#define NL 8
#define NV 100000
#define ND 64
#define WAVES_PER_BLOCK 4
#define BLOCK (WAVES_PER_BLOCK * 64)

__global__ __launch_bounds__(BLOCK, 4) void fwfm_kernel(
    const int*   __restrict__ idxs,   // [F,B,L]
    const float* __restrict__ wts,    // [F,B,L]
    const float* __restrict__ emb,    // [F,V,D]
    const float* __restrict__ lin_w,  // [F*D]
    const float* __restrict__ r,      // [F,F]
    const float* __restrict__ bias,   // [1]
    float*       __restrict__ out)    // [B]
{
    const int tid  = threadIdx.x;
    const int lane = tid & 63;
    // readfirstlane makes the wave id provably wave-uniform: b becomes
    // uniform -> idx/weight loads lower to s_load (scalar pipe, SGPRs),
    // row bases become SGPR pairs, and each gather is a single
    // global_load_dword v, v_laneoff, s[base] with one shared voffset.
    const int wave = __builtin_amdgcn_readfirstlane(tid >> 6);
    const int b    = blockIdx.x * WAVES_PER_BLOCK + wave;

    float acc[NF];

    // gather + weighted bag-sum: 208 coalesced 256B row loads per wave,
    // all addressing on the scalar pipe, weights ride in the SGPR slot
    // of v_fmac.
    #pragma unroll
    for (int f = 0; f < NF; ++f) {
        const float* tbl  = emb  + (size_t)f * ((size_t)NV * ND);
        const int*   bidx = idxs + (size_t)f * ((size_t)NB * NL) + (size_t)b * NL;
        const float* bwt  = wts  + (size_t)f * ((size_t)NB * NL) + (size_t)b * NL;
        float a = 0.f;
        #pragma unroll
        for (int l = 0; l < NL; ++l) {
            int   ix = bidx[l];   // uniform -> s_load
            float w  = bwt[l];    // uniform -> s_load
            a = fmaf(w, tbl[(size_t)ix * ND + lane], a);
        }
        acc[f] = a;
    }

    // linear term partial (lane-local over d)
    float part = 0.f;
    #pragma unroll
    for (int f = 0; f < NF; ++f)
        part = fmaf(acc[f], lin_w[f * ND + lane], part);

    // pairwise term: sum_{f<g} r[f,g] * v_f[d] * v_g[d]
    // r reads are uniform -> scalar loads, constant-cache resident.
    #pragma unroll
    for (int f = 0; f < NF; ++f) {
        float s = 0.f;
        #pragma unroll
        for (int g = f + 1; g < NF; ++g)
            s = fmaf(r[f * NF + g], acc[g], s);
        part = fmaf(acc[f], s, part);
    }

    // reduce over 64 lanes
    #pragma unroll
    for (int off = 32; off > 0; off >>= 1)
        part += __shfl_xor(part, off, 64);

    if (lane == 0) out[b] = part + bias[0];
}

extern "C" void kernel_launch(void* const* d_in, const int* in_sizes, int n_in,
                              void* d_out, int out_size, void* d_ws, size_t ws_size,
                              hipStream_t stream) {
    const int*   idxs  = (const int*)  d_in[0];
    const float* wts   = (const float*)d_in[1];
    const float* emb   = (const float*)d_in[2];
    const float* lin_w = (const float*)d_in[3];
    const float* r     = (const float*)d_in[4];
    const float* bias  = (const float*)d_in[5];
    float* out = (float*)d_out;

    dim3 grid(NB / WAVES_PER_BLOCK);
    dim3 block(BLOCK);
    fwfm_kernel<<<grid, block, 0, stream>>>(idxs, wts, emb, lin_w, r, bias, out);
}